// Round 11
// baseline (121.876 us; speedup 1.0000x reference)
//
#include <hip/hip_runtime.h>

typedef __attribute__((ext_vector_type(8))) short bf16x8;
typedef __attribute__((ext_vector_type(4))) float f32x4;
typedef __attribute__((ext_vector_type(2))) float f32x2;
typedef __attribute__((ext_vector_type(2))) unsigned int u32x2;
typedef __attribute__((ext_vector_type(4))) unsigned int u32x4;

// ---------------- new-path layout ----------------
#define PITCH     1056                                  // padded row pitch (elems)
#define AIM_BYTES ((size_t)25088 * PITCH * 2)           // im2col A, bf16
#define WEFF_OFF  AIM_BYTES
#define NEED_WS   (AIM_BYTES + (size_t)512 * PITCH * 2)
// ---------------- old-path (fallback) layout ----------------
#define XP_BYTES  (2048 * 3364 * 2)
#define BSTG_OFF  XP_BYTES

static __device__ __forceinline__ unsigned short f2bf(float v) {
    unsigned int u = __builtin_bit_cast(unsigned int, v);
    u += 0x7fffu + ((u >> 16) & 1u);
    return (unsigned short)(u >> 16);
}
static __device__ __forceinline__ void gload_lds16(const void* g, void* l) {
    __builtin_amdgcn_global_load_lds(
        (const __attribute__((address_space(1))) void*)g,
        (__attribute__((address_space(3))) void*)l, 16, 0, 0);
}

// ===========================================================================
// NEW PATH
// ===========================================================================

// prep2: bid<896 -> im2col producer (block = (nimg, row-group of 2 x-rows));
//        bid>=896 -> fold Hadamard transforms into weff (n-major, PITCH rows).
__global__ __launch_bounds__(256) void prep2(const float* __restrict__ x,
                                             const float* __restrict__ w,
                                             unsigned char* __restrict__ ws)
{
    int bid = blockIdx.x;
    unsigned short* aim = (unsigned short*)ws;
    if (bid < 896) {
        const int nimg = bid / 28, rg = bid - nimg * 28;
        const int grp = threadIdx.x >> 5, lw = threadIdx.x & 31;
        #pragma unroll 4
        for (int it = 0; it < 16; ++it) {
            int task = grp * 16 + it;              // 0..127
            int c = task >> 1, rr = task & 1, r = rg * 2 + rr;
            float v0 = 0.f, v1 = 0.f;
            if (lw < 28) {
                f32x2 xv = *(const f32x2*)(x + ((nimg * 64 + c) * 3136 + r * 56 + 2 * lw));
                v0 = xv[0]; v1 = xv[1];
            }
            float lf = __shfl_up(v1, 1, 32); if (lw == 0) lf = 0.f;
            float rt = __shfl_down(v0, 1, 32);     // lw=27 gets lane28's 0
            unsigned int lo = (unsigned int)f2bf(lf) | ((unsigned int)f2bf(v0) << 16);
            unsigned int hi = (unsigned int)f2bf(v1) | ((unsigned int)f2bf(rt) << 16);
            int h0, b0v, h1, b1v;
            if (r & 1) { b0v = 0; h0 = (r + 1) >> 1; b1v = 2; h1 = (r - 1) >> 1; }
            else       { b0v = 1; h0 = r >> 1;       b1v = 3; h1 = (r >> 1) - 1; }
            if (lw < 28) {
                int tb = nimg * 784 + lw;          // + h*28 below
                if (h0 >= 0 && h0 <= 27) {
                    u32x2 s = {lo, hi};
                    *(u32x2*)(aim + (size_t)(tb + h0 * 28) * PITCH + c * 16 + b0v * 4) = s;
                }
                if (h1 >= 0 && h1 <= 27) {
                    u32x2 s = {lo, hi};
                    *(u32x2*)(aim + (size_t)(tb + h1 * 28) * PITCH + c * 16 + b1v * 4) = s;
                }
                if (r == 0) {                      // (h=0,b=0): pad row, zeros
                    u32x2 z = {0u, 0u};
                    *(u32x2*)(aim + (size_t)tb * PITCH + c * 16) = z;
                }
                if (r == 55) {                     // (h=27,b=3): pad row, zeros
                    u32x2 z = {0u, 0u};
                    *(u32x2*)(aim + (size_t)(tb + 27 * 28) * PITCH + c * 16 + 12) = z;
                }
            }
        }
        return;
    }
    int idx = (bid - 896) * 256 + threadIdx.x;     // (o,c)
    if (idx >= 128 * 64) return;
    int o = idx >> 6, c = idx & 63;
    const bool v2 = (o >= 64);
    const float Hm[4][4]  = {{1,1,1,1},{1,-1,1,-1},{1,1,-1,-1},{1,-1,-1,1}};
    const float H2m[4][4] = {{1,-1,1,-1},{1,1,1,1},{1,1,-1,-1},{1,-1,-1,1}};
    float wv[4][4];
    #pragma unroll
    for (int i = 0; i < 4; ++i)
        #pragma unroll
        for (int j = 0; j < 4; ++j)
            wv[i][j] = w[((o * 64 + c) * 4 + i) * 4 + j];
    float FA[4][4], FB[4][4], G[2][4];
    #pragma unroll
    for (int a = 0; a < 4; ++a)
        #pragma unroll
        for (int i = 0; i < 4; ++i) {
            FA[a][i] = v2 ? H2m[a][i] : Hm[i][a];
            FB[a][i] = v2 ? H2m[a][i] : Hm[a][i];
        }
    #pragma unroll
    for (int p = 0; p < 2; ++p)
        #pragma unroll
        for (int i = 0; i < 4; ++i)
            G[p][i] = 0.25f * (v2 ? H2m[p + 1][i] : Hm[p + 1][i]);
    unsigned short* weff = (unsigned short*)(ws + WEFF_OFF);
    #pragma unroll
    for (int P = 0; P < 2; ++P)
    #pragma unroll
    for (int Q = 0; Q < 2; ++Q) {
        int nrow = o * 4 + P * 2 + Q;
        #pragma unroll
        for (int b = 0; b < 4; ++b)
        #pragma unroll
        for (int a = 0; a < 4; ++a) {
            float s = 0.f;
            #pragma unroll
            for (int i = 0; i < 4; ++i) {
                float sj = 0.f;
                #pragma unroll
                for (int j = 0; j < 4; ++j)
                    sj += FB[b][j] * G[Q][j] * wv[i][j];
                s += G[P][i] * FA[a][i] * sj;
            }
            weff[(size_t)nrow * PITCH + c * 16 + b * 4 + a] = f2bf(s);
        }
    }
}

// conv_gemm2: clean GEMM on materialized im2col.
// M=25088 (196x128), N=512 (4x128), K=1024 (16 x BK64).
// 512 thr = 8 waves (2m x 4n); wave 64x32 out, 16 MFMA/step.
// A+B staged via global_load_lds w=16 from pre-swizzled per-lane sources
// (rule #21), double-buffered, counted vmcnt(4) -- never drained.
__global__ __launch_bounds__(512, 4) void conv_gemm2(
    const unsigned short* __restrict__ aim,
    const unsigned short* __restrict__ weff,
    const float* __restrict__ bias,
    float* __restrict__ out)
{
    __shared__ __align__(16) unsigned char smem[66048];
    unsigned char* Ab0 = smem;                 // 2 x 16 KB
    unsigned char* Bb0 = smem + 32768;         // 2 x 16 KB
    int* s_obase = (int*)(smem + 65536);       // 128 ints

    const int tid  = threadIdx.x;
    const int lane = tid & 63;
    const int l15  = lane & 15;
    const int g    = lane >> 4;
    const int wv   = tid >> 6;                 // 0..7
    const int wm   = wv >> 2, wn = wv & 3;     // 2m x 4n
    const int bid  = blockIdx.x;
    const int wid  = (bid & 7) * 98 + (bid >> 3);   // XCD-chunked (784=8*98)
    const int tg   = wid >> 2, ng = wid & 3;
    const int t0   = tg << 7;
    const int n0g  = ng << 7;

    if (tid < 128) {
        int t = t0 + tid;
        int nimg = t / 784, rem = t - nimg * 784;
        int h = rem / 28, w = rem - h * 28;
        s_obase[tid] = nimg * 401408 + (2 * h) * 56 + 2 * w;
    }
    __syncthreads();

    // staging geometry: lane fills LDS row (wv*8 + lane/8 [+64q]) slot (lane&7);
    // source slot is XOR-permuted so swizzled reads see plain data (rule #21)
    const int arow = (wv << 3) + (lane >> 3);
    const int perm = (lane & 7) ^ (lane >> 3);
    const size_t a_src0 = (size_t)(t0 + arow) * PITCH + perm * 8;
    const size_t b_src0 = (size_t)(n0g + arow) * PITCH + perm * 8;

    const int fswz = (l15 & 7) << 4;
    int abase[4], bbase[2];
    #pragma unroll
    for (int fm = 0; fm < 4; ++fm)
        abase[fm] = (wm * 64 + fm * 16 + l15) * 128 + g * 16;
    #pragma unroll
    for (int fn = 0; fn < 2; ++fn)
        bbase[fn] = (wn * 32 + fn * 16 + l15) * 128 + g * 16;

    f32x4 acc[4][2];
    #pragma unroll
    for (int i = 0; i < 4; ++i)
        #pragma unroll
        for (int j = 0; j < 2; ++j)
            acc[i][j] = (f32x4){0.f, 0.f, 0.f, 0.f};

    auto STAGE = [&](int k, int buf) {
        const unsigned short* ga = aim + a_src0 + k * 64;
        const unsigned short* gb = weff + b_src0 + k * 64;
        unsigned char* al = Ab0 + buf * 16384 + wv * 1024;
        unsigned char* bl = Bb0 + buf * 16384 + wv * 1024;
        gload_lds16(ga,              al);
        gload_lds16(ga + 64 * PITCH, al + 8192);
        gload_lds16(gb,              bl);
        gload_lds16(gb + 64 * PITCH, bl + 8192);
    };
    auto MFMA_STEP = [&](int buf) {
        const unsigned char* A = Ab0 + buf * 16384;
        const unsigned char* B = Bb0 + buf * 16384;
        __builtin_amdgcn_s_setprio(1);
        #pragma unroll
        for (int ks = 0; ks < 2; ++ks) {
            bf16x8 af[4], bg[2];
            #pragma unroll
            for (int fm = 0; fm < 4; ++fm)
                af[fm] = *(const bf16x8*)(A + ((abase[fm] | (ks << 6)) ^ fswz));
            #pragma unroll
            for (int fn = 0; fn < 2; ++fn)
                bg[fn] = *(const bf16x8*)(B + ((bbase[fn] | (ks << 6)) ^ fswz));
            #pragma unroll
            for (int fm = 0; fm < 4; ++fm)
                #pragma unroll
                for (int fn = 0; fn < 2; ++fn)
                    acc[fm][fn] = __builtin_amdgcn_mfma_f32_16x16x32_bf16(
                        af[fm], bg[fn], acc[fm][fn], 0, 0, 0);
        }
        __builtin_amdgcn_s_setprio(0);
    };

    // prologue
    STAGE(0, 0);
    asm volatile("s_waitcnt vmcnt(0)" ::: "memory");
    __builtin_amdgcn_s_barrier();
    __builtin_amdgcn_sched_barrier(0);

    #pragma unroll 2
    for (int k = 0; k < 15; ++k) {
        STAGE(k + 1, (k + 1) & 1);                     // flies under MFMA(k)
        asm volatile("s_waitcnt vmcnt(4)" ::: "memory"); // step-k staging done
        __builtin_amdgcn_s_barrier();
        __builtin_amdgcn_sched_barrier(0);
        MFMA_STEP(k & 1);
        __builtin_amdgcn_s_barrier();                  // done reading buf k&1
        __builtin_amdgcn_sched_barrier(0);
    }
    asm volatile("s_waitcnt vmcnt(0)" ::: "memory");   // step-15 staging done
    __builtin_amdgcn_s_barrier();
    __builtin_amdgcn_sched_barrier(0);
    MFMA_STEP(1);
    __builtin_amdgcn_s_barrier();                      // before esc overwrite
    __builtin_amdgcn_sched_barrier(0);

    // epilogue: per-wave LDS transpose -> contiguous f32x2 stores
    float bfn[2];
    #pragma unroll
    for (int fn = 0; fn < 2; ++fn)
        bfn[fn] = bias[(n0g + wn * 32 + fn * 16 + l15) >> 2];
    const int ob = s_obase[wm * 64 + lane];
    float* esc = (float*)smem + wv * 1088;             // 64x17 per wave

    #pragma unroll
    for (int fn = 0; fn < 2; ++fn) {
        #pragma unroll
        for (int fm = 0; fm < 4; ++fm)
            #pragma unroll
            for (int r = 0; r < 4; ++r)
                esc[(fm * 16 + g * 4 + r) * 17 + l15] = acc[fm][fn][r] + bfn[fn];
        asm volatile("s_waitcnt lgkmcnt(0)" ::: "memory");
        __builtin_amdgcn_sched_barrier(0);
        const int ncb = n0g + wn * 32 + fn * 16;
        #pragma unroll
        for (int jp = 0; jp < 8; ++jp) {
            float v0 = esc[lane * 17 + 2 * jp];
            float v1 = esc[lane * 17 + 2 * jp + 1];
            int n = ncb + 2 * jp;
            int o = n >> 2, P = (n >> 1) & 1;
            f32x2 st = {v0, v1};
            *(f32x2*)(out + ob + o * 3136 + P * 56) = st;
        }
        asm volatile("s_waitcnt lgkmcnt(0)" ::: "memory");
        __builtin_amdgcn_sched_barrier(0);
    }
}

// ===========================================================================
// OLD PATH (fallback if ws too small) — round-7 kernels, verified passing
// ===========================================================================
__global__ __launch_bounds__(256) void prep_old(const float* __restrict__ x,
                                                const float* __restrict__ w,
                                                unsigned char* __restrict__ ws)
{
    int bid = blockIdx.x;
    if (bid < 2048) {
        const float* src = x + (size_t)bid * 3136;
        unsigned int* dst = (unsigned int*)ws + (size_t)bid * 1682;
        for (int s = threadIdx.x; s < 1682; s += 256) {
            int r = s / 29, p = s - r * 29;
            float v0 = 0.f, v1 = 0.f;
            if (r >= 1 && r <= 56) {
                const float* row = src + (r - 1) * 56;
                if (p >= 1)  v0 = row[2 * p - 1];
                if (p <= 27) v1 = row[2 * p];
            }
            dst[s] = (unsigned int)f2bf(v0) | ((unsigned int)f2bf(v1) << 16);
        }
        return;
    }
    int idx = (bid - 2048) * 256 + threadIdx.x;
    if (idx >= 128 * 64) return;
    int o = idx >> 6, c = idx & 63;
    const bool v2 = (o >= 64);
    const float Hm[4][4]  = {{1,1,1,1},{1,-1,1,-1},{1,1,-1,-1},{1,-1,-1,1}};
    const float H2m[4][4] = {{1,-1,1,-1},{1,1,1,1},{1,1,-1,-1},{1,-1,-1,1}};
    float wv[4][4];
    #pragma unroll
    for (int i = 0; i < 4; ++i)
        #pragma unroll
        for (int j = 0; j < 4; ++j)
            wv[i][j] = w[((o * 64 + c) * 4 + i) * 4 + j];
    float FA[4][4], FB[4][4], G[2][4];
    #pragma unroll
    for (int a = 0; a < 4; ++a)
        #pragma unroll
        for (int i = 0; i < 4; ++i) {
            FA[a][i] = v2 ? H2m[a][i] : Hm[i][a];
            FB[a][i] = v2 ? H2m[a][i] : Hm[a][i];
        }
    #pragma unroll
    for (int p = 0; p < 2; ++p)
        #pragma unroll
        for (int i = 0; i < 4; ++i)
            G[p][i] = 0.25f * (v2 ? H2m[p + 1][i] : Hm[p + 1][i]);
    unsigned short* weff = (unsigned short*)(ws + BSTG_OFF);
    #pragma unroll
    for (int P = 0; P < 2; ++P)
    #pragma unroll
    for (int Q = 0; Q < 2; ++Q) {
        int nrow = o * 4 + P * 2 + Q;
        #pragma unroll
        for (int b = 0; b < 4; ++b)
        #pragma unroll
        for (int a = 0; a < 4; ++a) {
            float s = 0.f;
            #pragma unroll
            for (int i = 0; i < 4; ++i) {
                float sj = 0.f;
                #pragma unroll
                for (int j = 0; j < 4; ++j)
                    sj += FB[b][j] * G[Q][j] * wv[i][j];
                s += G[P][i] * FA[a][i] * sj;
            }
            weff[(size_t)nrow * 1024 + c * 16 + b * 4 + a] = f2bf(s);
        }
    }
}

__global__ __launch_bounds__(256, 3) void conv_gemm_old(
    const unsigned short* __restrict__ xp,
    const unsigned short* __restrict__ weff,
    const float* __restrict__ bias,
    float* __restrict__ out)
{
    __shared__ __align__(16) unsigned char Abuf[2][16384];
    __shared__ int s_pbase[128];
    __shared__ int s_obase[128];
    const int tid  = threadIdx.x;
    const int lane = tid & 63;
    const int l15  = lane & 15;
    const int g    = lane >> 4;
    const int wv   = tid >> 6;
    const int wm   = wv >> 1, wn = wv & 1;
    const int bid  = blockIdx.x;
    const int wid = (bid & 7) * 98 + (bid >> 3);
    const int tg  = wid >> 2, ng = wid & 3;
    const int t0  = tg << 7;
    const int n0g = ng << 7;
    if (tid < 128) {
        int t = t0 + tid;
        int nimg = t / 784, rem = t - nimg * 784;
        int h = rem / 28, w = rem - h * 28;
        s_pbase[tid] = nimg * 215296 + (2 * h) * 58 + 2 * w;
        s_obase[tid] = nimg * 401408 + (2 * h) * 56 + 2 * w;
    }
    __syncthreads();
    const int t     = tid & 127;
    const int chalf = tid >> 7;
    const int ebase0 = s_pbase[t] + chalf * 6728;
    int wbyte[4];
    #pragma unroll
    for (int q = 0; q < 4; ++q)
        wbyte[q] = (t * 128 + chalf * 64 + q * 16) ^ ((t & 7) << 4);
    const int fswz = (l15 & 7) << 4;
    int abase[4];
    #pragma unroll
    for (int fm = 0; fm < 4; ++fm)
        abase[fm] = (wm * 64 + fm * 16 + l15) * 128 + g * 16;
    const char* bb = (const char*)weff;
    unsigned int boff[4];
    #pragma unroll
    for (int fn = 0; fn < 4; ++fn)
        boff[fn] = (unsigned)((n0g + wn * 64 + fn * 16 + l15) * 2048 + g * 16);
    f32x4 acc[4][4];
    #pragma unroll
    for (int i = 0; i < 4; ++i)
        #pragma unroll
        for (int j = 0; j < 4; ++j)
            acc[i][j] = (f32x4){0.f, 0.f, 0.f, 0.f};
    unsigned int Ar[16];
    bf16x8 bg[8];
    auto GATHER_A = [&](int k) {
        const unsigned short* p = xp + (ebase0 + k * 13456);
        #pragma unroll
        for (int cp = 0; cp < 2; ++cp)
            #pragma unroll
            for (int b = 0; b < 4; ++b) {
                const unsigned short* q = p + cp * 3364 + b * 58;
                Ar[cp * 8 + b * 2]     = *(const unsigned int*)(q);
                Ar[cp * 8 + b * 2 + 1] = *(const unsigned int*)(q + 2);
            }
    };
    auto STAGE_A = [&](int buf) {
        #pragma unroll
        for (int q = 0; q < 4; ++q) {
            u32x4 v = {Ar[q * 4], Ar[q * 4 + 1], Ar[q * 4 + 2], Ar[q * 4 + 3]};
            *(u32x4*)(Abuf[buf] + wbyte[q]) = v;
        }
    };
    auto LOAD_B = [&](int k) {
        const char* q = bb + (unsigned)k * 128u;
        #pragma unroll
        for (int fn = 0; fn < 4; ++fn)
            #pragma unroll
            for (int ks = 0; ks < 2; ++ks)
                bg[fn * 2 + ks] = *(const bf16x8*)(q + boff[fn] + ks * 64);
    };
    auto MFMA_STEP = [&](int buf) {
        const unsigned char* Ab = Abuf[buf];
        __builtin_amdgcn_s_setprio(1);
        #pragma unroll
        for (int ks = 0; ks < 2; ++ks) {
            bf16x8 af[4];
            #pragma unroll
            for (int fm = 0; fm < 4; ++fm)
                af[fm] = *(const bf16x8*)(Ab + ((abase[fm] | (ks << 6)) ^ fswz));
            #pragma unroll
            for (int fm = 0; fm < 4; ++fm)
                #pragma unroll
                for (int fn = 0; fn < 4; ++fn)
                    acc[fm][fn] = __builtin_amdgcn_mfma_f32_16x16x32_bf16(
                        af[fm], bg[fn * 2 + ks], acc[fm][fn], 0, 0, 0);
        }
        __builtin_amdgcn_s_setprio(0);
    };
    GATHER_A(0);
    STAGE_A(0);
    asm volatile("s_waitcnt lgkmcnt(0)" ::: "memory");
    __builtin_amdgcn_s_barrier();
    __builtin_amdgcn_sched_barrier(0);
#define STEP(K, LAST)                                                       \
    do {                                                                    \
        LOAD_B(K);                                                          \
        if (!(LAST)) GATHER_A((K) + 1);                                     \
        MFMA_STEP((K) & 1);                                                 \
        if (!(LAST)) {                                                      \
            STAGE_A(((K) + 1) & 1);                                         \
            asm volatile("s_waitcnt lgkmcnt(0)" ::: "memory");              \
            __builtin_amdgcn_s_barrier();                                   \
            __builtin_amdgcn_sched_barrier(0);                              \
        }                                                                   \
    } while (0)
    STEP(0, 0);  STEP(1, 0);  STEP(2, 0);  STEP(3, 0);
    STEP(4, 0);  STEP(5, 0);  STEP(6, 0);  STEP(7, 0);
    STEP(8, 0);  STEP(9, 0);  STEP(10, 0); STEP(11, 0);
    STEP(12, 0); STEP(13, 0); STEP(14, 0); STEP(15, 1);
#undef STEP
    float bfn[4];
    #pragma unroll
    for (int fn = 0; fn < 4; ++fn)
        bfn[fn] = bias[(n0g + wn * 64 + fn * 16 + l15) >> 2];
    const int ob = s_obase[wm * 64 + lane];
    asm volatile("s_waitcnt lgkmcnt(0)" ::: "memory");
    __builtin_amdgcn_s_barrier();
    __builtin_amdgcn_sched_barrier(0);
    float* esc = (float*)(&Abuf[0][0]) + wv * (64 * 17);
    #pragma unroll
    for (int fn = 0; fn < 4; ++fn) {
        #pragma unroll
        for (int fm = 0; fm < 4; ++fm)
            #pragma unroll
            for (int r = 0; r < 4; ++r)
                esc[(fm * 16 + g * 4 + r) * 17 + l15] = acc[fm][fn][r] + bfn[fn];
        asm volatile("s_waitcnt lgkmcnt(0)" ::: "memory");
        __builtin_amdgcn_sched_barrier(0);
        const int ncb = n0g + wn * 64 + fn * 16;
        #pragma unroll
        for (int jp = 0; jp < 8; ++jp) {
            float v0 = esc[lane * 17 + 2 * jp];
            float v1 = esc[lane * 17 + 2 * jp + 1];
            int n = ncb + 2 * jp;
            int o = n >> 2, P = (n >> 1) & 1;
            f32x2 st = {v0, v1};
            *(f32x2*)(out + ob + o * 3136 + P * 56) = st;
        }
        asm volatile("s_waitcnt lgkmcnt(0)" ::: "memory");
        __builtin_amdgcn_sched_barrier(0);
    }
}

extern "C" void kernel_launch(void* const* d_in, const int* in_sizes, int n_in,
                              void* d_out, int out_size, void* d_ws, size_t ws_size,
                              hipStream_t stream)
{
    const float* x = (const float*)d_in[0];
    const float* w = (const float*)d_in[1];
    const float* b = (const float*)d_in[2];
    float* out = (float*)d_out;
    unsigned char* ws = (unsigned char*)d_ws;

    if (ws_size >= NEED_WS) {
        hipLaunchKernelGGL(prep2, dim3(896 + 32), dim3(256), 0, stream, x, w, ws);
        hipLaunchKernelGGL(conv_gemm2, dim3(784), dim3(512), 0, stream,
                           (const unsigned short*)ws,
                           (const unsigned short*)(ws + WEFF_OFF), b, out);
    } else {
        hipLaunchKernelGGL(prep_old, dim3(2048 + 32), dim3(256), 0, stream, x, w, ws);
        hipLaunchKernelGGL(conv_gemm_old, dim3(784), dim3(256), 0, stream,
                           (const unsigned short*)ws,
                           (const unsigned short*)(ws + BSTG_OFF), b, out);
    }
}

// Round 12
// 61.257 us; speedup vs baseline: 1.9896x; 1.9896x over previous
//
#include <hip/hip_runtime.h>

typedef __attribute__((ext_vector_type(8))) short bf16x8;
typedef __attribute__((ext_vector_type(4))) float f32x4;
typedef __attribute__((ext_vector_type(2))) float f32x2;
typedef __attribute__((ext_vector_type(2))) unsigned int u32x2;
typedef __attribute__((ext_vector_type(4))) unsigned int u32x4;

// ---------------- new-path layout ----------------
#define PITCH     1056                                  // padded row pitch (elems)
#define AIM_BYTES ((size_t)25088 * PITCH * 2)           // im2col A, bf16
#define WEFF_OFF  AIM_BYTES
#define NEED_WS   (AIM_BYTES + (size_t)512 * PITCH * 2)
// ---------------- old-path (fallback) layout ----------------
#define XP_BYTES  (2048 * 3364 * 2)
#define BSTG_OFF  XP_BYTES

static __device__ __forceinline__ unsigned short f2bf(float v) {
    unsigned int u = __builtin_bit_cast(unsigned int, v);
    u += 0x7fffu + ((u >> 16) & 1u);
    return (unsigned short)(u >> 16);
}
static __device__ __forceinline__ void gload_lds16(const void* g, void* l) {
    __builtin_amdgcn_global_load_lds(
        (const __attribute__((address_space(1))) void*)g,
        (__attribute__((address_space(3))) void*)l, 16, 0, 0);
}

// ===========================================================================
// NEW PATH
// ===========================================================================

// prep3: bid<896 -> write-coalesced im2col producer. Block = (nimg, h).
//   LDS tap table: row R = c*4+b (256 rows), 66 bf16/row: col p in [0,57]
//   holds padded x(nimg, c, 2h+b-1, p-1); p=0,57 and invalid rows are 0.
//   Emit: out row t=(nimg*784+h*28+w), chunk q (16B) = LDS rows 2q,2q+1 at
//   word offset w -> contiguous 2048B per row, fully coalesced stores.
// bid>=896 -> fold Hadamard transforms into weff (n-major, PITCH rows).
__global__ __launch_bounds__(256) void prep3(const float* __restrict__ x,
                                             const float* __restrict__ w,
                                             unsigned char* __restrict__ ws)
{
    int bid = blockIdx.x;
    unsigned short* aim = (unsigned short*)ws;
    if (bid < 896) {
        __shared__ unsigned short lds[256 * 66];      // 33792 B
        const int nimg = bid / 28, h = bid - nimg * 28;
        const int tid = threadIdx.x;
        const int wv = tid >> 6, lane = tid & 63;

        // zero (covers pad cols 0/57 and boundary-invalid rows)
        unsigned int* l32 = (unsigned int*)lds;
        #pragma unroll
        for (int i = 0; i < 33; ++i)
            l32[tid + i * 256] = 0u;
        __syncthreads();

        // load: plane c rows 2h-1..2h+2 are contiguous (896B); 56 lanes x 16B
        const int b_off = (h == 0) ? 1 : 0;
        const int r0 = 2 * h - 1 + b_off;
        const int nrows = 4 - b_off - ((h == 27) ? 1 : 0);
        const int nelem = nrows * 56;
        const int e0 = lane * 4;
        #pragma unroll 4
        for (int i = 0; i < 16; ++i) {
            int c = wv * 16 + i;
            if (e0 < nelem) {
                const float* src = x + ((size_t)(nimg * 64 + c) * 3136 + r0 * 56);
                f32x4 v = *(const f32x4*)(src + e0);
                #pragma unroll
                for (int j = 0; j < 4; ++j) {
                    int e = e0 + j;
                    int rr = e / 56;
                    int col = e - rr * 56;
                    lds[(c * 4 + b_off + rr) * 66 + col + 1] = f2bf(v[j]);
                }
            }
        }
        __syncthreads();

        // emit: 2 rows per iter (tid>>7), 128 chunks per row (tid&127)
        const int q = tid & 127;
        const int wh = tid >> 7;
        const unsigned int* lr = (const unsigned int*)lds;   // word pitch 33
        const size_t trow0 = (size_t)nimg * 784 + h * 28;
        const int wa0 = (2 * q) * 33, wa1 = (2 * q + 1) * 33;
        #pragma unroll 7
        for (int it = 0; it < 14; ++it) {
            int wcol = it * 2 + wh;
            unsigned int a0 = lr[wa0 + wcol];
            unsigned int a1 = lr[wa0 + wcol + 1];
            unsigned int b0 = lr[wa1 + wcol];
            unsigned int b1 = lr[wa1 + wcol + 1];
            u32x4 st = {a0, a1, b0, b1};
            *(u32x4*)(aim + (trow0 + wcol) * PITCH + q * 8) = st;
        }
        return;
    }
    int idx = (bid - 896) * 256 + threadIdx.x;     // (o,c)
    if (idx >= 128 * 64) return;
    int o = idx >> 6, c = idx & 63;
    const bool v2 = (o >= 64);
    const float Hm[4][4]  = {{1,1,1,1},{1,-1,1,-1},{1,1,-1,-1},{1,-1,-1,1}};
    const float H2m[4][4] = {{1,-1,1,-1},{1,1,1,1},{1,1,-1,-1},{1,-1,-1,1}};
    float wv[4][4];
    #pragma unroll
    for (int i = 0; i < 4; ++i)
        #pragma unroll
        for (int j = 0; j < 4; ++j)
            wv[i][j] = w[((o * 64 + c) * 4 + i) * 4 + j];
    float FA[4][4], FB[4][4], G[2][4];
    #pragma unroll
    for (int a = 0; a < 4; ++a)
        #pragma unroll
        for (int i = 0; i < 4; ++i) {
            FA[a][i] = v2 ? H2m[a][i] : Hm[i][a];
            FB[a][i] = v2 ? H2m[a][i] : Hm[a][i];
        }
    #pragma unroll
    for (int p = 0; p < 2; ++p)
        #pragma unroll
        for (int i = 0; i < 4; ++i)
            G[p][i] = 0.25f * (v2 ? H2m[p + 1][i] : Hm[p + 1][i]);
    unsigned short* weff = (unsigned short*)(ws + WEFF_OFF);
    #pragma unroll
    for (int P = 0; P < 2; ++P)
    #pragma unroll
    for (int Q = 0; Q < 2; ++Q) {
        int nrow = o * 4 + P * 2 + Q;
        #pragma unroll
        for (int b = 0; b < 4; ++b)
        #pragma unroll
        for (int a = 0; a < 4; ++a) {
            float s = 0.f;
            #pragma unroll
            for (int i = 0; i < 4; ++i) {
                float sj = 0.f;
                #pragma unroll
                for (int j = 0; j < 4; ++j)
                    sj += FB[b][j] * G[Q][j] * wv[i][j];
                s += G[P][i] * FA[a][i] * sj;
            }
            weff[(size_t)nrow * PITCH + c * 16 + b * 4 + a] = f2bf(s);
        }
    }
}

// conv_gemm2: clean GEMM on materialized im2col (unchanged from r11, passed).
// M=25088 (196x128), N=512 (4x128), K=1024 (16 x BK64).
__global__ __launch_bounds__(512, 4) void conv_gemm2(
    const unsigned short* __restrict__ aim,
    const unsigned short* __restrict__ weff,
    const float* __restrict__ bias,
    float* __restrict__ out)
{
    __shared__ __align__(16) unsigned char smem[66048];
    unsigned char* Ab0 = smem;                 // 2 x 16 KB
    unsigned char* Bb0 = smem + 32768;         // 2 x 16 KB
    int* s_obase = (int*)(smem + 65536);       // 128 ints

    const int tid  = threadIdx.x;
    const int lane = tid & 63;
    const int l15  = lane & 15;
    const int g    = lane >> 4;
    const int wv   = tid >> 6;                 // 0..7
    const int wm   = wv >> 2, wn = wv & 3;     // 2m x 4n
    const int bid  = blockIdx.x;
    const int wid  = (bid & 7) * 98 + (bid >> 3);   // XCD-chunked (784=8*98)
    const int tg   = wid >> 2, ng = wid & 3;
    const int t0   = tg << 7;
    const int n0g  = ng << 7;

    if (tid < 128) {
        int t = t0 + tid;
        int nimg = t / 784, rem = t - nimg * 784;
        int h = rem / 28, w = rem - h * 28;
        s_obase[tid] = nimg * 401408 + (2 * h) * 56 + 2 * w;
    }
    __syncthreads();

    const int arow = (wv << 3) + (lane >> 3);
    const int perm = (lane & 7) ^ (lane >> 3);
    const size_t a_src0 = (size_t)(t0 + arow) * PITCH + perm * 8;
    const size_t b_src0 = (size_t)(n0g + arow) * PITCH + perm * 8;

    const int fswz = (l15 & 7) << 4;
    int abase[4], bbase[2];
    #pragma unroll
    for (int fm = 0; fm < 4; ++fm)
        abase[fm] = (wm * 64 + fm * 16 + l15) * 128 + g * 16;
    #pragma unroll
    for (int fn = 0; fn < 2; ++fn)
        bbase[fn] = (wn * 32 + fn * 16 + l15) * 128 + g * 16;

    f32x4 acc[4][2];
    #pragma unroll
    for (int i = 0; i < 4; ++i)
        #pragma unroll
        for (int j = 0; j < 2; ++j)
            acc[i][j] = (f32x4){0.f, 0.f, 0.f, 0.f};

    auto STAGE = [&](int k, int buf) {
        const unsigned short* ga = aim + a_src0 + k * 64;
        const unsigned short* gb = weff + b_src0 + k * 64;
        unsigned char* al = Ab0 + buf * 16384 + wv * 1024;
        unsigned char* bl = Bb0 + buf * 16384 + wv * 1024;
        gload_lds16(ga,              al);
        gload_lds16(ga + 64 * PITCH, al + 8192);
        gload_lds16(gb,              bl);
        gload_lds16(gb + 64 * PITCH, bl + 8192);
    };
    auto MFMA_STEP = [&](int buf) {
        const unsigned char* A = Ab0 + buf * 16384;
        const unsigned char* B = Bb0 + buf * 16384;
        __builtin_amdgcn_s_setprio(1);
        #pragma unroll
        for (int ks = 0; ks < 2; ++ks) {
            bf16x8 af[4], bg[2];
            #pragma unroll
            for (int fm = 0; fm < 4; ++fm)
                af[fm] = *(const bf16x8*)(A + ((abase[fm] | (ks << 6)) ^ fswz));
            #pragma unroll
            for (int fn = 0; fn < 2; ++fn)
                bg[fn] = *(const bf16x8*)(B + ((bbase[fn] | (ks << 6)) ^ fswz));
            #pragma unroll
            for (int fm = 0; fm < 4; ++fm)
                #pragma unroll
                for (int fn = 0; fn < 2; ++fn)
                    acc[fm][fn] = __builtin_amdgcn_mfma_f32_16x16x32_bf16(
                        af[fm], bg[fn], acc[fm][fn], 0, 0, 0);
        }
        __builtin_amdgcn_s_setprio(0);
    };

    STAGE(0, 0);
    asm volatile("s_waitcnt vmcnt(0)" ::: "memory");
    __builtin_amdgcn_s_barrier();
    __builtin_amdgcn_sched_barrier(0);

    #pragma unroll 2
    for (int k = 0; k < 15; ++k) {
        STAGE(k + 1, (k + 1) & 1);
        asm volatile("s_waitcnt vmcnt(4)" ::: "memory");
        __builtin_amdgcn_s_barrier();
        __builtin_amdgcn_sched_barrier(0);
        MFMA_STEP(k & 1);
        __builtin_amdgcn_s_barrier();
        __builtin_amdgcn_sched_barrier(0);
    }
    asm volatile("s_waitcnt vmcnt(0)" ::: "memory");
    __builtin_amdgcn_s_barrier();
    __builtin_amdgcn_sched_barrier(0);
    MFMA_STEP(1);
    __builtin_amdgcn_s_barrier();
    __builtin_amdgcn_sched_barrier(0);

    float bfn[2];
    #pragma unroll
    for (int fn = 0; fn < 2; ++fn)
        bfn[fn] = bias[(n0g + wn * 32 + fn * 16 + l15) >> 2];
    const int ob = s_obase[wm * 64 + lane];
    float* esc = (float*)smem + wv * 1088;

    #pragma unroll
    for (int fn = 0; fn < 2; ++fn) {
        #pragma unroll
        for (int fm = 0; fm < 4; ++fm)
            #pragma unroll
            for (int r = 0; r < 4; ++r)
                esc[(fm * 16 + g * 4 + r) * 17 + l15] = acc[fm][fn][r] + bfn[fn];
        asm volatile("s_waitcnt lgkmcnt(0)" ::: "memory");
        __builtin_amdgcn_sched_barrier(0);
        const int ncb = n0g + wn * 32 + fn * 16;
        #pragma unroll
        for (int jp = 0; jp < 8; ++jp) {
            float v0 = esc[lane * 17 + 2 * jp];
            float v1 = esc[lane * 17 + 2 * jp + 1];
            int n = ncb + 2 * jp;
            int o = n >> 2, P = (n >> 1) & 1;
            f32x2 st = {v0, v1};
            *(f32x2*)(out + ob + o * 3136 + P * 56) = st;
        }
        asm volatile("s_waitcnt lgkmcnt(0)" ::: "memory");
        __builtin_amdgcn_sched_barrier(0);
    }
}

// ===========================================================================
// OLD PATH (fallback if ws too small) — round-7 kernels, verified passing
// ===========================================================================
__global__ __launch_bounds__(256) void prep_old(const float* __restrict__ x,
                                                const float* __restrict__ w,
                                                unsigned char* __restrict__ ws)
{
    int bid = blockIdx.x;
    if (bid < 2048) {
        const float* src = x + (size_t)bid * 3136;
        unsigned int* dst = (unsigned int*)ws + (size_t)bid * 1682;
        for (int s = threadIdx.x; s < 1682; s += 256) {
            int r = s / 29, p = s - r * 29;
            float v0 = 0.f, v1 = 0.f;
            if (r >= 1 && r <= 56) {
                const float* row = src + (r - 1) * 56;
                if (p >= 1)  v0 = row[2 * p - 1];
                if (p <= 27) v1 = row[2 * p];
            }
            dst[s] = (unsigned int)f2bf(v0) | ((unsigned int)f2bf(v1) << 16);
        }
        return;
    }
    int idx = (bid - 2048) * 256 + threadIdx.x;
    if (idx >= 128 * 64) return;
    int o = idx >> 6, c = idx & 63;
    const bool v2 = (o >= 64);
    const float Hm[4][4]  = {{1,1,1,1},{1,-1,1,-1},{1,1,-1,-1},{1,-1,-1,1}};
    const float H2m[4][4] = {{1,-1,1,-1},{1,1,1,1},{1,1,-1,-1},{1,-1,-1,1}};
    float wv[4][4];
    #pragma unroll
    for (int i = 0; i < 4; ++i)
        #pragma unroll
        for (int j = 0; j < 4; ++j)
            wv[i][j] = w[((o * 64 + c) * 4 + i) * 4 + j];
    float FA[4][4], FB[4][4], G[2][4];
    #pragma unroll
    for (int a = 0; a < 4; ++a)
        #pragma unroll
        for (int i = 0; i < 4; ++i) {
            FA[a][i] = v2 ? H2m[a][i] : Hm[i][a];
            FB[a][i] = v2 ? H2m[a][i] : Hm[a][i];
        }
    #pragma unroll
    for (int p = 0; p < 2; ++p)
        #pragma unroll
        for (int i = 0; i < 4; ++i)
            G[p][i] = 0.25f * (v2 ? H2m[p + 1][i] : Hm[p + 1][i]);
    unsigned short* weff = (unsigned short*)(ws + BSTG_OFF);
    #pragma unroll
    for (int P = 0; P < 2; ++P)
    #pragma unroll
    for (int Q = 0; Q < 2; ++Q) {
        int nrow = o * 4 + P * 2 + Q;
        #pragma unroll
        for (int b = 0; b < 4; ++b)
        #pragma unroll
        for (int a = 0; a < 4; ++a) {
            float s = 0.f;
            #pragma unroll
            for (int i = 0; i < 4; ++i) {
                float sj = 0.f;
                #pragma unroll
                for (int j = 0; j < 4; ++j)
                    sj += FB[b][j] * G[Q][j] * wv[i][j];
                s += G[P][i] * FA[a][i] * sj;
            }
            weff[(size_t)nrow * 1024 + c * 16 + b * 4 + a] = f2bf(s);
        }
    }
}

__global__ __launch_bounds__(256, 3) void conv_gemm_old(
    const unsigned short* __restrict__ xp,
    const unsigned short* __restrict__ weff,
    const float* __restrict__ bias,
    float* __restrict__ out)
{
    __shared__ __align__(16) unsigned char Abuf[2][16384];
    __shared__ int s_pbase[128];
    __shared__ int s_obase[128];
    const int tid  = threadIdx.x;
    const int lane = tid & 63;
    const int l15  = lane & 15;
    const int g    = lane >> 4;
    const int wv   = tid >> 6;
    const int wm   = wv >> 1, wn = wv & 1;
    const int bid  = blockIdx.x;
    const int wid = (bid & 7) * 98 + (bid >> 3);
    const int tg  = wid >> 2, ng = wid & 3;
    const int t0  = tg << 7;
    const int n0g = ng << 7;
    if (tid < 128) {
        int t = t0 + tid;
        int nimg = t / 784, rem = t - nimg * 784;
        int h = rem / 28, w = rem - h * 28;
        s_pbase[tid] = nimg * 215296 + (2 * h) * 58 + 2 * w;
        s_obase[tid] = nimg * 401408 + (2 * h) * 56 + 2 * w;
    }
    __syncthreads();
    const int t     = tid & 127;
    const int chalf = tid >> 7;
    const int ebase0 = s_pbase[t] + chalf * 6728;
    int wbyte[4];
    #pragma unroll
    for (int q = 0; q < 4; ++q)
        wbyte[q] = (t * 128 + chalf * 64 + q * 16) ^ ((t & 7) << 4);
    const int fswz = (l15 & 7) << 4;
    int abase[4];
    #pragma unroll
    for (int fm = 0; fm < 4; ++fm)
        abase[fm] = (wm * 64 + fm * 16 + l15) * 128 + g * 16;
    const char* bb = (const char*)weff;
    unsigned int boff[4];
    #pragma unroll
    for (int fn = 0; fn < 4; ++fn)
        boff[fn] = (unsigned)((n0g + wn * 64 + fn * 16 + l15) * 2048 + g * 16);
    f32x4 acc[4][4];
    #pragma unroll
    for (int i = 0; i < 4; ++i)
        #pragma unroll
        for (int j = 0; j < 4; ++j)
            acc[i][j] = (f32x4){0.f, 0.f, 0.f, 0.f};
    unsigned int Ar[16];
    bf16x8 bg[8];
    auto GATHER_A = [&](int k) {
        const unsigned short* p = xp + (ebase0 + k * 13456);
        #pragma unroll
        for (int cp = 0; cp < 2; ++cp)
            #pragma unroll
            for (int b = 0; b < 4; ++b) {
                const unsigned short* q = p + cp * 3364 + b * 58;
                Ar[cp * 8 + b * 2]     = *(const unsigned int*)(q);
                Ar[cp * 8 + b * 2 + 1] = *(const unsigned int*)(q + 2);
            }
    };
    auto STAGE_A = [&](int buf) {
        #pragma unroll
        for (int q = 0; q < 4; ++q) {
            u32x4 v = {Ar[q * 4], Ar[q * 4 + 1], Ar[q * 4 + 2], Ar[q * 4 + 3]};
            *(u32x4*)(Abuf[buf] + wbyte[q]) = v;
        }
    };
    auto LOAD_B = [&](int k) {
        const char* q = bb + (unsigned)k * 128u;
        #pragma unroll
        for (int fn = 0; fn < 4; ++fn)
            #pragma unroll
            for (int ks = 0; ks < 2; ++ks)
                bg[fn * 2 + ks] = *(const bf16x8*)(q + boff[fn] + ks * 64);
    };
    auto MFMA_STEP = [&](int buf) {
        const unsigned char* Ab = Abuf[buf];
        __builtin_amdgcn_s_setprio(1);
        #pragma unroll
        for (int ks = 0; ks < 2; ++ks) {
            bf16x8 af[4];
            #pragma unroll
            for (int fm = 0; fm < 4; ++fm)
                af[fm] = *(const bf16x8*)(Ab + ((abase[fm] | (ks << 6)) ^ fswz));
            #pragma unroll
            for (int fm = 0; fm < 4; ++fm)
                #pragma unroll
                for (int fn = 0; fn < 4; ++fn)
                    acc[fm][fn] = __builtin_amdgcn_mfma_f32_16x16x32_bf16(
                        af[fm], bg[fn * 2 + ks], acc[fm][fn], 0, 0, 0);
        }
        __builtin_amdgcn_s_setprio(0);
    };
    GATHER_A(0);
    STAGE_A(0);
    asm volatile("s_waitcnt lgkmcnt(0)" ::: "memory");
    __builtin_amdgcn_s_barrier();
    __builtin_amdgcn_sched_barrier(0);
#define STEP(K, LAST)                                                       \
    do {                                                                    \
        LOAD_B(K);                                                          \
        if (!(LAST)) GATHER_A((K) + 1);                                     \
        MFMA_STEP((K) & 1);                                                 \
        if (!(LAST)) {                                                      \
            STAGE_A(((K) + 1) & 1);                                         \
            asm volatile("s_waitcnt lgkmcnt(0)" ::: "memory");              \
            __builtin_amdgcn_s_barrier();                                   \
            __builtin_amdgcn_sched_barrier(0);                              \
        }                                                                   \
    } while (0)
    STEP(0, 0);  STEP(1, 0);  STEP(2, 0);  STEP(3, 0);
    STEP(4, 0);  STEP(5, 0);  STEP(6, 0);  STEP(7, 0);
    STEP(8, 0);  STEP(9, 0);  STEP(10, 0); STEP(11, 0);
    STEP(12, 0); STEP(13, 0); STEP(14, 0); STEP(15, 1);
#undef STEP
    float bfn[4];
    #pragma unroll
    for (int fn = 0; fn < 4; ++fn)
        bfn[fn] = bias[(n0g + wn * 64 + fn * 16 + l15) >> 2];
    const int ob = s_obase[wm * 64 + lane];
    asm volatile("s_waitcnt lgkmcnt(0)" ::: "memory");
    __builtin_amdgcn_s_barrier();
    __builtin_amdgcn_sched_barrier(0);
    float* esc = (float*)(&Abuf[0][0]) + wv * (64 * 17);
    #pragma unroll
    for (int fn = 0; fn < 4; ++fn) {
        #pragma unroll
        for (int fm = 0; fm < 4; ++fm)
            #pragma unroll
            for (int r = 0; r < 4; ++r)
                esc[(fm * 16 + g * 4 + r) * 17 + l15] = acc[fm][fn][r] + bfn[fn];
        asm volatile("s_waitcnt lgkmcnt(0)" ::: "memory");
        __builtin_amdgcn_sched_barrier(0);
        const int ncb = n0g + wn * 64 + fn * 16;
        #pragma unroll
        for (int jp = 0; jp < 8; ++jp) {
            float v0 = esc[lane * 17 + 2 * jp];
            float v1 = esc[lane * 17 + 2 * jp + 1];
            int n = ncb + 2 * jp;
            int o = n >> 2, P = (n >> 1) & 1;
            f32x2 st = {v0, v1};
            *(f32x2*)(out + ob + o * 3136 + P * 56) = st;
        }
        asm volatile("s_waitcnt lgkmcnt(0)" ::: "memory");
        __builtin_amdgcn_sched_barrier(0);
    }
}

extern "C" void kernel_launch(void* const* d_in, const int* in_sizes, int n_in,
                              void* d_out, int out_size, void* d_ws, size_t ws_size,
                              hipStream_t stream)
{
    const float* x = (const float*)d_in[0];
    const float* w = (const float*)d_in[1];
    const float* b = (const float*)d_in[2];
    float* out = (float*)d_out;
    unsigned char* ws = (unsigned char*)d_ws;

    if (ws_size >= NEED_WS) {
        hipLaunchKernelGGL(prep3, dim3(896 + 32), dim3(256), 0, stream, x, w, ws);
        hipLaunchKernelGGL(conv_gemm2, dim3(784), dim3(512), 0, stream,
                           (const unsigned short*)ws,
                           (const unsigned short*)(ws + WEFF_OFF), b, out);
    } else {
        hipLaunchKernelGGL(prep_old, dim3(2048 + 32), dim3(256), 0, stream, x, w, ws);
        hipLaunchKernelGGL(conv_gemm_old, dim3(784), dim3(256), 0, stream,
                           (const unsigned short*)ws,
                           (const unsigned short*)(ws + BSTG_OFF), b, out);
    }
}